// Round 8
// baseline (72.660 us; speedup 1.0000x reference)
//
#include <hip/hip_runtime.h>

#define DIM    64      // CELL_DIM
#define NCELLS 512
#define ROWS_PER_BLOCK 32
#define NROWS  8192
#define NBLOCKS (NROWS / ROWS_PER_BLOCK)   // 256 = one block per CU
#define PCT_FLOATS (DIM * NCELLS)                  // 32768 fp32 = 128 KB
#define XT_FLOATS  (ROWS_PER_BLOCK * DIM)          // 2048 fp32 = 8 KB
#define LDS_BYTES  ((PCT_FLOATS + XT_FLOATS) * 4)  // 136 KB <= 160 KB/CU

// R8: halve LDS-read traffic via 4 rows/wave. R7's body model: 16 waves each
// read the whole 128 KB pcT -> 2 MB/CU of ds_read_b128 at 85 B/cyc = 10.2 us,
// ABOVE the 6.8 us VALU floor -> LDS-read-pipe bound. With 4 rows/wave each
// read-pair feeds 128 VALU-cycles: 1 MB/CU = 5 us < VALU floor -> VALU-bound.
// (R5 tried 4 rows/wave but with per-k4 VMEM x loads at 2 waves/SIMD; global
// latency masked the LDS relief. R7 removed VMEM from the body, exposing it.)
// Geometry: 512 thr = 8 waves x 4 rows = 32 rows/block, 1 block/CU, ONE barrier.
// Accumulators are named float4s (R2 lesson: no runtime-selected refs/indices).
__global__ __launch_bounds__(512, 2)
void placecells_kernel(const float* __restrict__ x,
                       const float* __restrict__ pc,
                       float* __restrict__ out)
{
    extern __shared__ float lds[];
    float* pcT = lds;                 // [64 k][512 cells], quad-swizzled
    float* xT  = lds + PCT_FLOATS;    // [32 rows][64 k], row-major

    const int tid = (int)threadIdx.x;
    const int l   = tid & 63;
    const int w   = __builtin_amdgcn_readfirstlane(tid >> 6);
    const int rowBase = (int)blockIdx.x * ROWS_PER_BLOCK + w * 4;

    // ---- stage x slice (8 KB): 2048 floats over 512 threads, coalesced ----
    {
        float4 v = *(const float4*)(x + (size_t)blockIdx.x * ROWS_PER_BLOCK * DIM + 4 * tid);
        *(float4*)(&xT[4 * tid]) = v;
    }

    // ---- stage pc (128 KB): batched loads-then-writes (one vmcnt batch x2) ----
    auto pc_ld = [&](int i) -> float4 {          // i compile-time at call sites
        int idx = i * 512 + tid;                 // 0..8191
        int cl  = idx >> 4;                      // cell, 0..511
        int kq  = idx & 15;                      // k-quad, 0..15
        return *(const float4*)(pc + cl * DIM + kq * 4);
    };
    auto pc_st = [&](int i, float4 v) {
        int idx = i * 512 + tid;
        int cl  = idx >> 4;
        int kq  = idx & 15;
        int pq  = (cl >> 2) ^ kq;                // quad swizzle (write spread)
        float* p = &pcT[(kq * 4) * NCELLS + pq * 4 + (cl & 3)];
        p[0 * NCELLS] = v.x;
        p[1 * NCELLS] = v.y;
        p[2 * NCELLS] = v.z;
        p[3 * NCELLS] = v.w;
    };
    {
        float4 s0 = pc_ld(0), s1 = pc_ld(1), s2 = pc_ld(2), s3 = pc_ld(3);
        float4 s4 = pc_ld(4), s5 = pc_ld(5), s6 = pc_ld(6), s7 = pc_ld(7);
        pc_st(0, s0); pc_st(1, s1); pc_st(2, s2); pc_st(3, s3);
        pc_st(4, s4); pc_st(5, s5); pc_st(6, s6); pc_st(7, s7);
    }
    {
        float4 s8 = pc_ld(8),  s9 = pc_ld(9),  sA = pc_ld(10), sB = pc_ld(11);
        float4 sC = pc_ld(12), sD = pc_ld(13), sE = pc_ld(14), sF = pc_ld(15);
        pc_st(8, s8);  pc_st(9, s9);  pc_st(10, sA); pc_st(11, sB);
        pc_st(12, sC); pc_st(13, sD); pc_st(14, sE); pc_st(15, sF);
    }

    __syncthreads();   // the ONLY barrier in the kernel

    // a{row}{chunk}: 4 rows x 2 chunks x 4 cells -> 32 accumulator VGPRs
    float4 a0A{0,0,0,0}, a0B{0,0,0,0};
    float4 a1A{0,0,0,0}, a1B{0,0,0,0};
    float4 a2A{0,0,0,0}, a2B{0,0,0,0};
    float4 a3A{0,0,0,0}, a3B{0,0,0,0};

    // hoisted wave-uniform x row bases: x reads are uniform-address ds_read_b128
    // with compile-time offset immediates (broadcast, conflict-free)
    const float* xr0 = &xT[(w * 4 + 0) * DIM];
    const float* xr1 = &xT[(w * 4 + 1) * DIM];
    const float* xr2 = &xT[(w * 4 + 2) * DIM];
    const float* xr3 = &xT[(w * 4 + 3) * DIM];

    // ---- K loop: fully unrolled; per j, 2 conflict-free ds_read_b128 feed
    //      4 rows x 8 cells x 2 ops = 64 VALU instructions ----
    #pragma unroll
    for (int k4 = 0; k4 < 16; ++k4) {
        float4 xv0 = *(const float4*)(xr0 + k4 * 4);
        float4 xv1 = *(const float4*)(xr1 + k4 * 4);
        float4 xv2 = *(const float4*)(xr2 + k4 * 4);
        float4 xv3 = *(const float4*)(xr3 + k4 * 4);
        const int pqA = (l ^ k4) * 4;     // undo swizzle: logical quad = l
        #pragma unroll
        for (int j = 0; j < 4; ++j) {
            const float* rowp = &pcT[(k4 * 4 + j) * NCELLS];
            float4 pvA = *(const float4*)(rowp + pqA);        // cells 4l..4l+3
            float4 pvB = *(const float4*)(rowp + pqA + 256);  // cells 256+4l..+3
            float x0 = (j == 0) ? xv0.x : (j == 1) ? xv0.y : (j == 2) ? xv0.z : xv0.w;
            float x1 = (j == 0) ? xv1.x : (j == 1) ? xv1.y : (j == 2) ? xv1.z : xv1.w;
            float x2 = (j == 0) ? xv2.x : (j == 1) ? xv2.y : (j == 2) ? xv2.z : xv2.w;
            float x3 = (j == 0) ? xv3.x : (j == 1) ? xv3.y : (j == 2) ? xv3.z : xv3.w;
            a0A.x += fabsf(x0 - pvA.x); a0A.y += fabsf(x0 - pvA.y);
            a0A.z += fabsf(x0 - pvA.z); a0A.w += fabsf(x0 - pvA.w);
            a0B.x += fabsf(x0 - pvB.x); a0B.y += fabsf(x0 - pvB.y);
            a0B.z += fabsf(x0 - pvB.z); a0B.w += fabsf(x0 - pvB.w);
            a1A.x += fabsf(x1 - pvA.x); a1A.y += fabsf(x1 - pvA.y);
            a1A.z += fabsf(x1 - pvA.z); a1A.w += fabsf(x1 - pvA.w);
            a1B.x += fabsf(x1 - pvB.x); a1B.y += fabsf(x1 - pvB.y);
            a1B.z += fabsf(x1 - pvB.z); a1B.w += fabsf(x1 - pvB.w);
            a2A.x += fabsf(x2 - pvA.x); a2A.y += fabsf(x2 - pvA.y);
            a2A.z += fabsf(x2 - pvA.z); a2A.w += fabsf(x2 - pvA.w);
            a2B.x += fabsf(x2 - pvB.x); a2B.y += fabsf(x2 - pvB.y);
            a2B.z += fabsf(x2 - pvB.z); a2B.w += fabsf(x2 - pvB.w);
            a3A.x += fabsf(x3 - pvA.x); a3A.y += fabsf(x3 - pvA.y);
            a3A.z += fabsf(x3 - pvA.z); a3A.w += fabsf(x3 - pvA.w);
            a3B.x += fabsf(x3 - pvB.x); a3B.y += fabsf(x3 - pvB.y);
            a3B.z += fabsf(x3 - pvB.z); a3B.w += fabsf(x3 - pvB.w);
        }
    }

    // ---- softmax tail: all 4 rows interleaved (independent dep chains) ----
    {
        float mn0 = fminf(fminf(fminf(a0A.x, a0A.y), fminf(a0A.z, a0A.w)),
                          fminf(fminf(a0B.x, a0B.y), fminf(a0B.z, a0B.w)));
        float mn1 = fminf(fminf(fminf(a1A.x, a1A.y), fminf(a1A.z, a1A.w)),
                          fminf(fminf(a1B.x, a1B.y), fminf(a1B.z, a1B.w)));
        float mn2 = fminf(fminf(fminf(a2A.x, a2A.y), fminf(a2A.z, a2A.w)),
                          fminf(fminf(a2B.x, a2B.y), fminf(a2B.z, a2B.w)));
        float mn3 = fminf(fminf(fminf(a3A.x, a3A.y), fminf(a3A.z, a3A.w)),
                          fminf(fminf(a3B.x, a3B.y), fminf(a3B.z, a3B.w)));
        #pragma unroll
        for (int off = 32; off > 0; off >>= 1) {
            mn0 = fminf(mn0, __shfl_xor(mn0, off, 64));
            mn1 = fminf(mn1, __shfl_xor(mn1, off, 64));
            mn2 = fminf(mn2, __shfl_xor(mn2, off, 64));
            mn3 = fminf(mn3, __shfl_xor(mn3, off, 64));
        }
        float m20 = mn0 * mn0, m21 = mn1 * mn1, m22 = mn2 * mn2, m23 = mn3 * mn3;

        float e00 = __expf(0.5f * (m20 - a0A.x * a0A.x));
        float e01 = __expf(0.5f * (m20 - a0A.y * a0A.y));
        float e02 = __expf(0.5f * (m20 - a0A.z * a0A.z));
        float e03 = __expf(0.5f * (m20 - a0A.w * a0A.w));
        float e04 = __expf(0.5f * (m20 - a0B.x * a0B.x));
        float e05 = __expf(0.5f * (m20 - a0B.y * a0B.y));
        float e06 = __expf(0.5f * (m20 - a0B.z * a0B.z));
        float e07 = __expf(0.5f * (m20 - a0B.w * a0B.w));
        float e10 = __expf(0.5f * (m21 - a1A.x * a1A.x));
        float e11 = __expf(0.5f * (m21 - a1A.y * a1A.y));
        float e12 = __expf(0.5f * (m21 - a1A.z * a1A.z));
        float e13 = __expf(0.5f * (m21 - a1A.w * a1A.w));
        float e14 = __expf(0.5f * (m21 - a1B.x * a1B.x));
        float e15 = __expf(0.5f * (m21 - a1B.y * a1B.y));
        float e16 = __expf(0.5f * (m21 - a1B.z * a1B.z));
        float e17 = __expf(0.5f * (m21 - a1B.w * a1B.w));
        float e20 = __expf(0.5f * (m22 - a2A.x * a2A.x));
        float e21 = __expf(0.5f * (m22 - a2A.y * a2A.y));
        float e22 = __expf(0.5f * (m22 - a2A.z * a2A.z));
        float e23 = __expf(0.5f * (m22 - a2A.w * a2A.w));
        float e24 = __expf(0.5f * (m22 - a2B.x * a2B.x));
        float e25 = __expf(0.5f * (m22 - a2B.y * a2B.y));
        float e26 = __expf(0.5f * (m22 - a2B.z * a2B.z));
        float e27 = __expf(0.5f * (m22 - a2B.w * a2B.w));
        float e30 = __expf(0.5f * (m23 - a3A.x * a3A.x));
        float e31 = __expf(0.5f * (m23 - a3A.y * a3A.y));
        float e32 = __expf(0.5f * (m23 - a3A.z * a3A.z));
        float e33 = __expf(0.5f * (m23 - a3A.w * a3A.w));
        float e34 = __expf(0.5f * (m23 - a3B.x * a3B.x));
        float e35 = __expf(0.5f * (m23 - a3B.y * a3B.y));
        float e36 = __expf(0.5f * (m23 - a3B.z * a3B.z));
        float e37 = __expf(0.5f * (m23 - a3B.w * a3B.w));

        float sum0 = ((e00 + e01) + (e02 + e03)) + ((e04 + e05) + (e06 + e07));
        float sum1 = ((e10 + e11) + (e12 + e13)) + ((e14 + e15) + (e16 + e17));
        float sum2 = ((e20 + e21) + (e22 + e23)) + ((e24 + e25) + (e26 + e27));
        float sum3 = ((e30 + e31) + (e32 + e33)) + ((e34 + e35) + (e36 + e37));
        #pragma unroll
        for (int off = 32; off > 0; off >>= 1) {
            sum0 += __shfl_xor(sum0, off, 64);
            sum1 += __shfl_xor(sum1, off, 64);
            sum2 += __shfl_xor(sum2, off, 64);
            sum3 += __shfl_xor(sum3, off, 64);
        }
        float inv0 = 1.0f / sum0, inv1 = 1.0f / sum1;
        float inv2 = 1.0f / sum2, inv3 = 1.0f / sum3;

        float* orow0 = out + (size_t)(rowBase + 0) * NCELLS;
        float* orow1 = out + (size_t)(rowBase + 1) * NCELLS;
        float* orow2 = out + (size_t)(rowBase + 2) * NCELLS;
        float* orow3 = out + (size_t)(rowBase + 3) * NCELLS;
        *(float4*)(orow0 + 4 * l)       = make_float4(e00 * inv0, e01 * inv0, e02 * inv0, e03 * inv0);
        *(float4*)(orow0 + 256 + 4 * l) = make_float4(e04 * inv0, e05 * inv0, e06 * inv0, e07 * inv0);
        *(float4*)(orow1 + 4 * l)       = make_float4(e10 * inv1, e11 * inv1, e12 * inv1, e13 * inv1);
        *(float4*)(orow1 + 256 + 4 * l) = make_float4(e14 * inv1, e15 * inv1, e16 * inv1, e17 * inv1);
        *(float4*)(orow2 + 4 * l)       = make_float4(e20 * inv2, e21 * inv2, e22 * inv2, e23 * inv2);
        *(float4*)(orow2 + 256 + 4 * l) = make_float4(e24 * inv2, e25 * inv2, e26 * inv2, e27 * inv2);
        *(float4*)(orow3 + 4 * l)       = make_float4(e30 * inv3, e31 * inv3, e32 * inv3, e33 * inv3);
        *(float4*)(orow3 + 256 + 4 * l) = make_float4(e34 * inv3, e35 * inv3, e36 * inv3, e37 * inv3);
    }
}

extern "C" void kernel_launch(void* const* d_in, const int* in_sizes, int n_in,
                              void* d_out, int out_size, void* d_ws, size_t ws_size,
                              hipStream_t stream)
{
    const float* x  = (const float*)d_in[0];   // (8192, 64) fp32
    const float* pc = (const float*)d_in[1];   // (512, 64) fp32
    float* out = (float*)d_out;                // (8192, 512) fp32
    placecells_kernel<<<dim3(NBLOCKS), dim3(512), LDS_BYTES, stream>>>(x, pc, out);
}